// Round 1
// baseline (867.248 us; speedup 1.0000x reference)
//
#include <hip/hip_runtime.h>
#include <math.h>

#define NB 16
#define NN 768
#define NT 48
#define ND 2048
#define SCALE 0.02209708691207961f   // 1/sqrt(2048)
#define NEGBIG (-3.4028234663852886e38f)

// ---------------- kernel A: rms-norm task tokens ----------------
__global__ __launch_bounds__(256) void k_task_norm(const float* __restrict__ x,
                                                   float* __restrict__ y) {
    __shared__ float sred[8];
    const int row = blockIdx.x;                 // b*NT + t
    const float4* src = (const float4*)(x + (size_t)row * ND);
    float4* dst = (float4*)(y + (size_t)row * ND);
    const int tid = threadIdx.x;
    float4 v0 = src[tid];
    float4 v1 = src[tid + 256];
    float s = v0.x*v0.x + v0.y*v0.y + v0.z*v0.z + v0.w*v0.w
            + v1.x*v1.x + v1.y*v1.y + v1.z*v1.z + v1.w*v1.w;
    #pragma unroll
    for (int off = 32; off > 0; off >>= 1) s += __shfl_down(s, off, 64);
    if ((tid & 63) == 0) sred[tid >> 6] = s;
    __syncthreads();
    if (tid == 0)
        sred[4] = 1.0f / sqrtf((sred[0]+sred[1]+sred[2]+sred[3]) * (1.0f/ND) + 1e-6f);
    __syncthreads();
    const float inv = sred[4];
    v0.x *= inv; v0.y *= inv; v0.z *= inv; v0.w *= inv;
    v1.x *= inv; v1.y *= inv; v1.z *= inv; v1.w *= inv;
    dst[tid] = v0;
    dst[tid + 256] = v1;
}

// ---------------- kernel B: per-row inverse rms of patches ----------------
__global__ __launch_bounds__(256) void k_pinv(const float* __restrict__ x,
                                              float* __restrict__ pinv) {
    __shared__ float sred[8];
    const int row = blockIdx.x;                 // b*NN + n
    const float4* src = (const float4*)(x + (size_t)row * ND);
    const int tid = threadIdx.x;
    float4 v0 = src[tid];
    float4 v1 = src[tid + 256];
    float s = v0.x*v0.x + v0.y*v0.y + v0.z*v0.z + v0.w*v0.w
            + v1.x*v1.x + v1.y*v1.y + v1.z*v1.z + v1.w*v1.w;
    #pragma unroll
    for (int off = 32; off > 0; off >>= 1) s += __shfl_down(s, off, 64);
    if ((tid & 63) == 0) sred[tid >> 6] = s;
    __syncthreads();
    if (tid == 0)
        pinv[row] = 1.0f / sqrtf((sred[0]+sred[1]+sred[2]+sred[3]) * (1.0f/ND) + 1e-6f);
}

// ---------------- kernel C: attention -> queries_raw ----------------
// block: (row-tile of 32 patch rows, b). 256 threads.
__global__ __launch_bounds__(256) void k_attn(const float* __restrict__ patches,
                                              const float* __restrict__ task_n,
                                              const float* __restrict__ pinv,
                                              const int* __restrict__ mask,
                                              float* __restrict__ qraw) {
    __shared__ float smem[12672];   // phase1: Pt[32][68] + Tt[48][68]; phase2: Tt2[48][264]
    __shared__ float lg[32 * 52];   // logits -> attn, stride 52 (bank-friendly)
    const int rt  = blockIdx.x;
    const int b   = blockIdx.y;
    const int r0  = rt * 32;
    const int tid = threadIdx.x;

    float* Pt = smem;               // [32][68]
    float* Tt = smem + 32 * 68;     // [48][68]
    const size_t pbase = ((size_t)b * NN + r0) * ND;
    const size_t tbase = (size_t)b * NT * ND;

    // ---- phase 1: raw logits[32][48] ----
    const int rg = tid >> 4;        // 0..15 -> rows {rg, rg+16}
    const int tg = tid & 15;        // 0..15 -> t {tg, tg+16, tg+32}
    float acc0[3] = {0.f, 0.f, 0.f};
    float acc1[3] = {0.f, 0.f, 0.f};
    for (int d0 = 0; d0 < ND; d0 += 64) {
        {   // stage Pt (512 float4, 2/thread)
            int fi = tid, row = fi >> 4, c4 = fi & 15;
            *(float4*)&Pt[row*68 + c4*4] =
                *(const float4*)&patches[pbase + (size_t)row*ND + d0 + c4*4];
            fi = tid + 256; row = fi >> 4; c4 = fi & 15;
            *(float4*)&Pt[row*68 + c4*4] =
                *(const float4*)&patches[pbase + (size_t)row*ND + d0 + c4*4];
        }
        #pragma unroll
        for (int k = 0; k < 3; k++) {   // stage Tt (768 float4, 3/thread)
            int fi = tid + 256*k, row = fi >> 4, c4 = fi & 15;
            *(float4*)&Tt[row*68 + c4*4] =
                *(const float4*)&task_n[tbase + (size_t)row*ND + d0 + c4*4];
        }
        __syncthreads();
        #pragma unroll 4
        for (int k4 = 0; k4 < 16; k4++) {
            float4 q0 = *(float4*)&Pt[rg*68 + k4*4];
            float4 q1 = *(float4*)&Pt[(rg+16)*68 + k4*4];
            #pragma unroll
            for (int j = 0; j < 3; j++) {
                float4 t4 = *(float4*)&Tt[(tg + 16*j)*68 + k4*4];
                acc0[j] += q0.x*t4.x + q0.y*t4.y + q0.z*t4.z + q0.w*t4.w;
                acc1[j] += q1.x*t4.x + q1.y*t4.y + q1.z*t4.z + q1.w*t4.w;
            }
        }
        __syncthreads();
    }
    {   // scaled logits + mask bias
        const float pr0 = pinv[(size_t)b*NN + r0 + rg] * SCALE;
        const float pr1 = pinv[(size_t)b*NN + r0 + rg + 16] * SCALE;
        #pragma unroll
        for (int j = 0; j < 3; j++) {
            const int t = tg + 16*j;
            const float bias = mask[b*NT + t] ? 0.0f : NEGBIG;
            lg[rg*52 + t]      = acc0[j] * pr0 + bias;
            lg[(rg+16)*52 + t] = acc1[j] * pr1 + bias;
        }
    }
    __syncthreads();
    // ---- softmax per row (32 threads) ----
    if (tid < 32) {
        float mx = -INFINITY;
        for (int t = 0; t < NT; t++) mx = fmaxf(mx, lg[tid*52 + t]);
        float sum = 0.f;
        for (int t = 0; t < NT; t++) {
            float e = expf(lg[tid*52 + t] - mx);
            lg[tid*52 + t] = e;
            sum += e;
        }
        const float inv = 1.0f / sum;
        for (int t = 0; t < NT; t++) lg[tid*52 + t] *= inv;
    }
    __syncthreads();
    // ---- phase 2: queries_raw = attn @ task_n ----
    float* Tt2 = smem;              // [48][264]
    const int rg2 = tid >> 5;       // 0..7 -> rows rg2*4 .. +3
    const int dg  = tid & 31;       // 8 floats each
    for (int d0 = 0; d0 < ND; d0 += 256) {
        #pragma unroll
        for (int k = 0; k < 12; k++) {   // stage Tt2 (3072 float4, 12/thread)
            int fi = tid + 256*k, row = fi >> 6, c4 = fi & 63;
            *(float4*)&Tt2[row*264 + c4*4] =
                *(const float4*)&task_n[tbase + (size_t)row*ND + d0 + c4*4];
        }
        __syncthreads();
        float4 a[4][2] = {};
        for (int t = 0; t < NT; t++) {
            float4 u0 = *(float4*)&Tt2[t*264 + dg*8];
            float4 u1 = *(float4*)&Tt2[t*264 + dg*8 + 4];
            #pragma unroll
            for (int i = 0; i < 4; i++) {
                const float w = lg[(rg2*4 + i)*52 + t];
                a[i][0].x += w*u0.x; a[i][0].y += w*u0.y; a[i][0].z += w*u0.z; a[i][0].w += w*u0.w;
                a[i][1].x += w*u1.x; a[i][1].y += w*u1.y; a[i][1].z += w*u1.z; a[i][1].w += w*u1.w;
            }
        }
        #pragma unroll
        for (int i = 0; i < 4; i++) {
            const size_t o = ((size_t)b*NN + r0 + rg2*4 + i)*ND + d0 + dg*8;
            *(float4*)&qraw[o]     = a[i][0];
            *(float4*)&qraw[o + 4] = a[i][1];
        }
        __syncthreads();
    }
}

// ---------------- kernel D: score + argmax ----------------
// grid (12 row-tiles, 4 m-splits, B); BM=64, BN=64, 4x4 per thread (strided 16).
__global__ __launch_bounds__(256) void k_score(const float* __restrict__ patches,
                                               const float* __restrict__ qraw,
                                               const float* __restrict__ pinv,
                                               unsigned long long* __restrict__ keys) {
    __shared__ float Qt[64 * 68];
    __shared__ float Pt[64 * 68];
    __shared__ float redv[64 * 17];
    __shared__ int   redm[64 * 17];
    const int rt  = blockIdx.x;
    const int ms  = blockIdx.y;
    const int b   = blockIdx.z;
    const int r0  = rt * 64;
    const int tid = threadIdx.x;
    const int ty  = tid >> 4;       // rows {ty, ty+16, ty+32, ty+48}
    const int tx  = tid & 15;       // cols {tx, tx+16, tx+32, tx+48}

    float bestv[4] = {-INFINITY, -INFINITY, -INFINITY, -INFINITY};
    int   bestm[4] = {0, 0, 0, 0};

    for (int mt = 0; mt < 3; mt++) {
        const int m0 = (ms*3 + mt) * 64;
        float acc[4][4] = {};
        for (int d0 = 0; d0 < ND; d0 += 64) {
            #pragma unroll
            for (int k = 0; k < 4; k++) {   // stage Qt & Pt (1024 float4 each)
                int fi = tid + 256*k, row = fi >> 4, c4 = fi & 15;
                *(float4*)&Qt[row*68 + c4*4] =
                    *(const float4*)&qraw[((size_t)b*NN + r0 + row)*ND + d0 + c4*4];
                *(float4*)&Pt[row*68 + c4*4] =
                    *(const float4*)&patches[((size_t)b*NN + m0 + row)*ND + d0 + c4*4];
            }
            __syncthreads();
            #pragma unroll 4
            for (int k4 = 0; k4 < 16; k4++) {
                float4 q[4], p[4];
                #pragma unroll
                for (int i = 0; i < 4; i++) q[i] = *(float4*)&Qt[(ty + 16*i)*68 + k4*4];
                #pragma unroll
                for (int j = 0; j < 4; j++) p[j] = *(float4*)&Pt[(tx + 16*j)*68 + k4*4];
                #pragma unroll
                for (int i = 0; i < 4; i++)
                    #pragma unroll
                    for (int j = 0; j < 4; j++)
                        acc[i][j] += q[i].x*p[j].x + q[i].y*p[j].y
                                   + q[i].z*p[j].z + q[i].w*p[j].w;
            }
            __syncthreads();
        }
        #pragma unroll
        for (int j = 0; j < 4; j++) {
            const int m = m0 + tx + 16*j;
            const float pv = pinv[(size_t)b*NN + m];
            #pragma unroll
            for (int i = 0; i < 4; i++) {
                const float v = acc[i][j] * pv;
                if (v > bestv[i] || (v == bestv[i] && m < bestm[i])) {
                    bestv[i] = v; bestm[i] = m;
                }
            }
        }
    }
    #pragma unroll
    for (int i = 0; i < 4; i++) {
        const int lr = ty + 16*i;
        redv[lr*17 + tx] = bestv[i];
        redm[lr*17 + tx] = bestm[i];
    }
    __syncthreads();
    if (tid < 64) {
        float bv = redv[tid*17];
        int   bm = redm[tid*17];
        #pragma unroll
        for (int k = 1; k < 16; k++) {
            const float v = redv[tid*17 + k];
            const int   m = redm[tid*17 + k];
            if (v > bv || (v == bv && m < bm)) { bv = v; bm = m; }
        }
        unsigned u = __float_as_uint(bv);
        u = (u & 0x80000000u) ? ~u : (u | 0x80000000u);
        const unsigned long long key =
            ((unsigned long long)u << 32) | (unsigned)(NN - 1 - bm);
        atomicMax(&keys[(size_t)b*NN + r0 + tid], key);
    }
}

// ---------------- kernel E: one-hot writer ----------------
__global__ __launch_bounds__(256) void k_onehot(const unsigned long long* __restrict__ keys,
                                                float* __restrict__ out) {
    const int g = blockIdx.x * 256 + threadIdx.x;      // float4 index
    const int row = g / (NN/4);
    const int j4  = g % (NN/4);
    const unsigned long long key = keys[row];
    const int m = NN - 1 - (int)(key & 0xFFFFFFFFull);
    float4 o = {0.f, 0.f, 0.f, 0.f};
    if ((m >> 2) == j4) ((float*)&o)[m & 3] = 1.0f;
    ((float4*)out)[g] = o;
}

// ---------------- launcher ----------------
extern "C" void kernel_launch(void* const* d_in, const int* in_sizes, int n_in,
                              void* d_out, int out_size, void* d_ws, size_t ws_size,
                              hipStream_t stream) {
    const float* patches = (const float*)d_in[0];
    const float* task    = (const float*)d_in[1];
    const int*   mask    = (const int*)d_in[2];

    float* ws     = (float*)d_ws;
    float* task_n = ws;                                  // 16*48*2048
    float* pinv   = task_n + (size_t)NB*NT*ND;           // 12288
    float* qraw   = pinv + (size_t)NB*NN;                // 16*768*2048
    unsigned long long* keys =
        (unsigned long long*)(qraw + (size_t)NB*NN*ND);  // 12288 u64
    float* out = (float*)d_out;

    hipMemsetAsync(keys, 0, (size_t)NB*NN*sizeof(unsigned long long), stream);
    k_task_norm<<<NB*NT, 256, 0, stream>>>(task, task_n);
    k_pinv<<<NB*NN, 256, 0, stream>>>(patches, pinv);
    k_attn<<<dim3(NN/32, NB), 256, 0, stream>>>(patches, task_n, pinv, mask, qraw);
    k_score<<<dim3(NN/64, 4, NB), 256, 0, stream>>>(patches, qraw, pinv, keys);
    k_onehot<<<(NB*NN*NN/4)/256, 256, 0, stream>>>(keys, out);
}

// Round 2
// 349.995 us; speedup vs baseline: 2.4779x; 2.4779x over previous
//
#include <hip/hip_runtime.h>
#include <math.h>

#define NB 16
#define NN 768
#define NT 48
#define ND 2048
#define SCALE 0.02209708691207961f   // 1/sqrt(2048)
#define NEGBIG (-3.4028234663852886e38f)
#define TAU 1e-3f

typedef _Float16 f16;
typedef f16  f16x8 __attribute__((ext_vector_type(8)));
typedef f16  f16x4 __attribute__((ext_vector_type(4)));
typedef float f32x4 __attribute__((ext_vector_type(4)));

__device__ __forceinline__ void stage16(const void* g, void* l) {
    __builtin_amdgcn_global_load_lds(
        (const __attribute__((address_space(1))) unsigned int*)g,
        (__attribute__((address_space(3))) unsigned int*)l, 16, 0, 0);
}

// ---------------- kernel A: rms-norm task tokens ----------------
__global__ __launch_bounds__(256) void k_task_norm(const float* __restrict__ x,
                                                   float* __restrict__ y) {
    __shared__ float sred[8];
    const int row = blockIdx.x;                 // b*NT + t
    const float4* src = (const float4*)(x + (size_t)row * ND);
    float4* dst = (float4*)(y + (size_t)row * ND);
    const int tid = threadIdx.x;
    float4 v0 = src[tid];
    float4 v1 = src[tid + 256];
    float s = v0.x*v0.x + v0.y*v0.y + v0.z*v0.z + v0.w*v0.w
            + v1.x*v1.x + v1.y*v1.y + v1.z*v1.z + v1.w*v1.w;
    #pragma unroll
    for (int off = 32; off > 0; off >>= 1) s += __shfl_down(s, off, 64);
    if ((tid & 63) == 0) sred[tid >> 6] = s;
    __syncthreads();
    if (tid == 0)
        sred[4] = 1.0f / sqrtf((sred[0]+sred[1]+sred[2]+sred[3]) * (1.0f/ND) + 1e-6f);
    __syncthreads();
    const float inv = sred[4];
    v0.x *= inv; v0.y *= inv; v0.z *= inv; v0.w *= inv;
    v1.x *= inv; v1.y *= inv; v1.z *= inv; v1.w *= inv;
    dst[tid] = v0;
    dst[tid + 256] = v1;
}

// ---------------- kernel B (old path): per-row inverse rms of patches ----------------
__global__ __launch_bounds__(256) void k_pinv(const float* __restrict__ x,
                                              float* __restrict__ pinv) {
    __shared__ float sred[8];
    const int row = blockIdx.x;                 // b*NN + n
    const float4* src = (const float4*)(x + (size_t)row * ND);
    const int tid = threadIdx.x;
    float4 v0 = src[tid];
    float4 v1 = src[tid + 256];
    float s = v0.x*v0.x + v0.y*v0.y + v0.z*v0.z + v0.w*v0.w
            + v1.x*v1.x + v1.y*v1.y + v1.z*v1.z + v1.w*v1.w;
    #pragma unroll
    for (int off = 32; off > 0; off >>= 1) s += __shfl_down(s, off, 64);
    if ((tid & 63) == 0) sred[tid >> 6] = s;
    __syncthreads();
    if (tid == 0)
        pinv[row] = 1.0f / sqrtf((sred[0]+sred[1]+sred[2]+sred[3]) * (1.0f/ND) + 1e-6f);
}

// ---------------- kernel B' (new path): pinv + fp16 hi/lo split of patches ----------------
__global__ __launch_bounds__(256) void k_split_patches(const float* __restrict__ x,
                                                       float* __restrict__ pinv,
                                                       f16* __restrict__ p_hi,
                                                       f16* __restrict__ p_lo) {
    __shared__ float sred[8];
    const int row = blockIdx.x;                 // b*NN + n
    const float4* src = (const float4*)(x + (size_t)row * ND);
    const int tid = threadIdx.x;
    float4 v0 = src[tid];
    float4 v1 = src[tid + 256];
    float s = v0.x*v0.x + v0.y*v0.y + v0.z*v0.z + v0.w*v0.w
            + v1.x*v1.x + v1.y*v1.y + v1.z*v1.z + v1.w*v1.w;
    #pragma unroll
    for (int off = 32; off > 0; off >>= 1) s += __shfl_down(s, off, 64);
    if ((tid & 63) == 0) sred[tid >> 6] = s;
    __syncthreads();
    if (tid == 0)
        pinv[row] = 1.0f / sqrtf((sred[0]+sred[1]+sred[2]+sred[3]) * (1.0f/ND) + 1e-6f);
    f16x4 h0, l0, h1, l1;
    #pragma unroll
    for (int e = 0; e < 4; e++) {
        float f0 = (&v0.x)[e], f1 = (&v1.x)[e];
        f16 a = (f16)f0; h0[e] = a; l0[e] = (f16)(f0 - (float)a);
        f16 c = (f16)f1; h1[e] = c; l1[e] = (f16)(f1 - (float)c);
    }
    const size_t o = (size_t)row * ND;
    *(f16x4*)&p_hi[o + tid*4] = h0;
    *(f16x4*)&p_lo[o + tid*4] = l0;
    *(f16x4*)&p_hi[o + (tid+256)*4] = h1;
    *(f16x4*)&p_lo[o + (tid+256)*4] = l1;
}

// ---------------- kernel C: attention -> queries (fp32 and/or fp16 split) ----------------
__global__ __launch_bounds__(256) void k_attn(const float* __restrict__ patches,
                                              const float* __restrict__ task_n,
                                              const float* __restrict__ pinv,
                                              const int* __restrict__ mask,
                                              float* __restrict__ qraw,
                                              f16* __restrict__ q_hi,
                                              f16* __restrict__ q_lo) {
    __shared__ float smem[12672];   // phase1: Pt[32][68] + Tt[48][68]; phase2: Tt2[48][264]
    __shared__ float lg[32 * 52];   // logits -> attn, stride 52
    const int rt  = blockIdx.x;
    const int b   = blockIdx.y;
    const int r0  = rt * 32;
    const int tid = threadIdx.x;

    float* Pt = smem;               // [32][68]
    float* Tt = smem + 32 * 68;     // [48][68]
    const size_t pbase = ((size_t)b * NN + r0) * ND;
    const size_t tbase = (size_t)b * NT * ND;

    const int rg = tid >> 4;
    const int tg = tid & 15;
    float acc0[3] = {0.f, 0.f, 0.f};
    float acc1[3] = {0.f, 0.f, 0.f};
    for (int d0 = 0; d0 < ND; d0 += 64) {
        {
            int fi = tid, row = fi >> 4, c4 = fi & 15;
            *(float4*)&Pt[row*68 + c4*4] =
                *(const float4*)&patches[pbase + (size_t)row*ND + d0 + c4*4];
            fi = tid + 256; row = fi >> 4; c4 = fi & 15;
            *(float4*)&Pt[row*68 + c4*4] =
                *(const float4*)&patches[pbase + (size_t)row*ND + d0 + c4*4];
        }
        #pragma unroll
        for (int k = 0; k < 3; k++) {
            int fi = tid + 256*k, row = fi >> 4, c4 = fi & 15;
            *(float4*)&Tt[row*68 + c4*4] =
                *(const float4*)&task_n[tbase + (size_t)row*ND + d0 + c4*4];
        }
        __syncthreads();
        #pragma unroll 4
        for (int k4 = 0; k4 < 16; k4++) {
            float4 q0 = *(float4*)&Pt[rg*68 + k4*4];
            float4 q1 = *(float4*)&Pt[(rg+16)*68 + k4*4];
            #pragma unroll
            for (int j = 0; j < 3; j++) {
                float4 t4 = *(float4*)&Tt[(tg + 16*j)*68 + k4*4];
                acc0[j] += q0.x*t4.x + q0.y*t4.y + q0.z*t4.z + q0.w*t4.w;
                acc1[j] += q1.x*t4.x + q1.y*t4.y + q1.z*t4.z + q1.w*t4.w;
            }
        }
        __syncthreads();
    }
    {
        const float pr0 = pinv[(size_t)b*NN + r0 + rg] * SCALE;
        const float pr1 = pinv[(size_t)b*NN + r0 + rg + 16] * SCALE;
        #pragma unroll
        for (int j = 0; j < 3; j++) {
            const int t = tg + 16*j;
            const float bias = mask[b*NT + t] ? 0.0f : NEGBIG;
            lg[rg*52 + t]      = acc0[j] * pr0 + bias;
            lg[(rg+16)*52 + t] = acc1[j] * pr1 + bias;
        }
    }
    __syncthreads();
    if (tid < 32) {
        float mx = -INFINITY;
        for (int t = 0; t < NT; t++) mx = fmaxf(mx, lg[tid*52 + t]);
        float sum = 0.f;
        for (int t = 0; t < NT; t++) {
            float e = expf(lg[tid*52 + t] - mx);
            lg[tid*52 + t] = e;
            sum += e;
        }
        const float inv = 1.0f / sum;
        for (int t = 0; t < NT; t++) lg[tid*52 + t] *= inv;
    }
    __syncthreads();
    float* Tt2 = smem;              // [48][264]
    const int rg2 = tid >> 5;
    const int dg  = tid & 31;
    for (int d0 = 0; d0 < ND; d0 += 256) {
        #pragma unroll
        for (int k = 0; k < 12; k++) {
            int fi = tid + 256*k, row = fi >> 6, c4 = fi & 63;
            *(float4*)&Tt2[row*264 + c4*4] =
                *(const float4*)&task_n[tbase + (size_t)row*ND + d0 + c4*4];
        }
        __syncthreads();
        float4 a[4][2] = {};
        for (int t = 0; t < NT; t++) {
            float4 u0 = *(float4*)&Tt2[t*264 + dg*8];
            float4 u1 = *(float4*)&Tt2[t*264 + dg*8 + 4];
            #pragma unroll
            for (int i = 0; i < 4; i++) {
                const float w = lg[(rg2*4 + i)*52 + t];
                a[i][0].x += w*u0.x; a[i][0].y += w*u0.y; a[i][0].z += w*u0.z; a[i][0].w += w*u0.w;
                a[i][1].x += w*u1.x; a[i][1].y += w*u1.y; a[i][1].z += w*u1.z; a[i][1].w += w*u1.w;
            }
        }
        #pragma unroll
        for (int i = 0; i < 4; i++) {
            const size_t o = ((size_t)b*NN + r0 + rg2*4 + i)*ND + d0 + dg*8;
            if (qraw) {
                *(float4*)&qraw[o]     = a[i][0];
                *(float4*)&qraw[o + 4] = a[i][1];
            }
            if (q_hi) {
                f16x8 vh, vl;
                #pragma unroll
                for (int e = 0; e < 4; e++) {
                    float f0 = (&a[i][0].x)[e], f1 = (&a[i][1].x)[e];
                    f16 h0 = (f16)f0, h1 = (f16)f1;
                    vh[e]   = h0; vl[e]   = (f16)(f0 - (float)h0);
                    vh[4+e] = h1; vl[4+e] = (f16)(f1 - (float)h1);
                }
                *(f16x8*)&q_hi[o] = vh;
                *(f16x8*)&q_lo[o] = vl;
            }
        }
        __syncthreads();
    }
}

// ---------------- kernel D (new): MFMA score + per-block top-2 ----------------
// tile BM=96 x BN=192, BK=64; grid (4 mt, 8 rt, 16 b) = 512 blocks = 2/CU exactly.
__global__ __launch_bounds__(256, 2) void k_score_mfma(
        const f16* __restrict__ p_hi, const f16* __restrict__ p_lo,
        const f16* __restrict__ q_hi, const f16* __restrict__ q_lo,
        const float* __restrict__ pinv, float4* __restrict__ part) {
    __shared__ f16 Ah[96*64], Al[96*64], Bh[192*64], Bl[192*64];   // 72 KB
    __shared__ float4 red[4*96];                                   // 6 KB
    const int mt = blockIdx.x, rt = blockIdx.y, b = blockIdx.z;
    const int tid = threadIdx.x, wid = tid >> 6, lane = tid & 63;
    const int q15 = lane & 15, g4 = lane >> 4;

    const int arow_g = b*NN + rt*96;
    const int brow_g = b*NN + mt*192;
    const f16* gAh = q_hi + (size_t)arow_g * ND;
    const f16* gAl = q_lo + (size_t)arow_g * ND;
    const f16* gBh = p_hi + (size_t)brow_g * ND;
    const f16* gBl = p_lo + (size_t)brow_g * ND;

    // staging: 8 rows (1 KB) per gload_lds instr; source chunk XOR-swizzled so
    // LDS[r][c] = G[r][c ^ (r&7)] with linear LDS dest (rule #21).
    const int lgch = (lane & 7) ^ (lane >> 3);
    unsigned aoff[3], boff[6];
    int ar0[3], br0[6];
    #pragma unroll
    for (int t = 0; t < 3; t++) {
        int r0 = (wid*3 + t) * 8;
        ar0[t] = r0;
        aoff[t] = (unsigned)((r0 + (lane>>3))*ND + 8*lgch);
    }
    #pragma unroll
    for (int t = 0; t < 6; t++) {
        int r0 = (wid*6 + t) * 8;
        br0[t] = r0;
        boff[t] = (unsigned)((r0 + (lane>>3))*ND + 8*lgch);
    }
    const int ch0 = g4 ^ (q15 & 7);   // read-side chunk for k-sub 0; sub 1 -> ^4

    f32x4 acc[6][3];
    #pragma unroll
    for (int i = 0; i < 6; i++)
        #pragma unroll
        for (int j = 0; j < 3; j++) acc[i][j] = (f32x4){0.f, 0.f, 0.f, 0.f};

    for (int k0 = 0; k0 < ND; k0 += 64) {
        #pragma unroll
        for (int t = 0; t < 3; t++) {
            stage16(gAh + aoff[t] + k0, &Ah[ar0[t]*64]);
            stage16(gAl + aoff[t] + k0, &Al[ar0[t]*64]);
        }
        #pragma unroll
        for (int t = 0; t < 6; t++) {
            stage16(gBh + boff[t] + k0, &Bh[br0[t]*64]);
            stage16(gBl + boff[t] + k0, &Bl[br0[t]*64]);
        }
        __syncthreads();
        #pragma unroll
        for (int s = 0; s < 2; s++) {
            const int ch = (ch0 ^ (s << 2)) * 8;
            f16x8 ah[6], al[6], bh[3], bl[3];
            #pragma unroll
            for (int i = 0; i < 6; i++) {
                ah[i] = *(const f16x8*)&Ah[(i*16 + q15)*64 + ch];
                al[i] = *(const f16x8*)&Al[(i*16 + q15)*64 + ch];
            }
            #pragma unroll
            for (int j = 0; j < 3; j++) {
                bh[j] = *(const f16x8*)&Bh[(wid*48 + j*16 + q15)*64 + ch];
                bl[j] = *(const f16x8*)&Bl[(wid*48 + j*16 + q15)*64 + ch];
            }
            #pragma unroll
            for (int i = 0; i < 6; i++)
                #pragma unroll
                for (int j = 0; j < 3; j++) {
                    acc[i][j] = __builtin_amdgcn_mfma_f32_16x16x32_f16(ah[i], bh[j], acc[i][j], 0, 0, 0);
                    acc[i][j] = __builtin_amdgcn_mfma_f32_16x16x32_f16(ah[i], bl[j], acc[i][j], 0, 0, 0);
                    acc[i][j] = __builtin_amdgcn_mfma_f32_16x16x32_f16(al[i], bh[j], acc[i][j], 0, 0, 0);
                }
        }
        __syncthreads();
    }

    // epilogue: scale by pinv[m], per-row top-2 (value desc, index asc on ties)
    const int base_m = mt*192 + wid*48;
    float pv[3];
    #pragma unroll
    for (int j = 0; j < 3; j++) pv[j] = pinv[b*NN + base_m + j*16 + q15];
    #pragma unroll
    for (int i = 0; i < 6; i++) {
        #pragma unroll
        for (int r = 0; r < 4; r++) {
            float v1 = -INFINITY, v2 = -INFINITY; int i1 = 0;
            #pragma unroll
            for (int j = 0; j < 3; j++) {
                float v = acc[i][j][r] * pv[j];
                int m = base_m + j*16 + q15;
                if (v > v1) { v2 = v1; v1 = v; i1 = m; }
                else if (v > v2) v2 = v;
            }
            #pragma unroll
            for (int msk = 1; msk <= 8; msk <<= 1) {
                float ov1 = __shfl_xor(v1, msk, 64);
                int   oi1 = __shfl_xor(i1, msk, 64);
                float ov2 = __shfl_xor(v2, msk, 64);
                if (ov1 > v1 || (ov1 == v1 && oi1 < i1)) { v2 = fmaxf(v1, ov2); v1 = ov1; i1 = oi1; }
                else v2 = fmaxf(v2, ov1);
            }
            if (q15 == 0)
                red[wid*96 + i*16 + g4*4 + r] = make_float4(v1, __int_as_float(i1), v2, 0.f);
        }
    }
    __syncthreads();
    if (tid < 96) {
        float4 e = red[tid];
        float v1 = e.x, v2 = e.z; int i1 = __float_as_int(e.y);
        #pragma unroll
        for (int w = 1; w < 4; w++) {
            float4 f = red[w*96 + tid];
            int fi = __float_as_int(f.y);
            if (f.x > v1 || (f.x == v1 && fi < i1)) { v2 = fmaxf(v1, f.z); v1 = f.x; i1 = fi; }
            else v2 = fmaxf(v2, f.x);
        }
        part[(size_t)(b*NN + rt*96 + tid)*4 + mt] = make_float4(v1, __int_as_float(i1), v2, 0.f);
    }
}

// ---------------- kernel E (new): merge m-tiles -> idx + rescore flag ----------------
__global__ __launch_bounds__(256) void k_merge(const float4* __restrict__ part,
                                               int* __restrict__ idxarr,
                                               int* __restrict__ flags) {
    const int r = blockIdx.x * 256 + threadIdx.x;
    float4 e = part[(size_t)r*4];
    float v1 = e.x, v2 = e.z; int i1 = __float_as_int(e.y);
    #pragma unroll
    for (int t = 1; t < 4; t++) {
        float4 f = part[(size_t)r*4 + t];
        int fi = __float_as_int(f.y);
        if (f.x > v1 || (f.x == v1 && fi < i1)) { v2 = fmaxf(v1, f.z); v1 = f.x; i1 = fi; }
        else v2 = fmaxf(v2, f.x);
    }
    idxarr[r] = i1;
    flags[r] = (v1 - v2 < TAU) ? 1 : 0;
}

// ---------------- kernel F (new): exact fp32 rescore of ambiguous rows ----------------
__global__ __launch_bounds__(256) void k_rescore(const float* __restrict__ patches,
                                                 const f16* __restrict__ q_hi,
                                                 const f16* __restrict__ q_lo,
                                                 const float* __restrict__ pinv,
                                                 const int* __restrict__ flags,
                                                 int* __restrict__ idxarr) {
    const int row = blockIdx.x;
    if (!flags[row]) return;
    __shared__ float qrow[ND];
    __shared__ float sv[256];
    __shared__ int   si[256];
    const int b = row / NN;
    const int tid = threadIdx.x;
    const size_t qo = (size_t)row * ND;
    #pragma unroll
    for (int e = 0; e < 8; e++)
        qrow[tid*8 + e] = (float)q_hi[qo + tid*8 + e] + (float)q_lo[qo + tid*8 + e];
    __syncthreads();
    float bv = -INFINITY; int bm = 0;
    for (int mm = tid; mm < NN; mm += 256) {
        const float4* prow = (const float4*)(patches + ((size_t)b*NN + mm)*ND);
        float s = 0.f;
        for (int d4 = 0; d4 < ND/4; d4++) {
            float4 p = prow[d4];
            float4 qv = *(const float4*)&qrow[d4*4];
            s = fmaf(p.x, qv.x, s); s = fmaf(p.y, qv.y, s);
            s = fmaf(p.z, qv.z, s); s = fmaf(p.w, qv.w, s);
        }
        s *= pinv[(size_t)b*NN + mm];
        if (s > bv) { bv = s; bm = mm; }
    }
    sv[tid] = bv; si[tid] = bm;
    __syncthreads();
    for (int st = 128; st > 0; st >>= 1) {
        if (tid < st) {
            float v = sv[tid+st]; int m = si[tid+st];
            if (v > sv[tid] || (v == sv[tid] && m < si[tid])) { sv[tid] = v; si[tid] = m; }
        }
        __syncthreads();
    }
    if (tid == 0) idxarr[row] = si[0];
}

// ---------------- kernel G (new): one-hot from idx ----------------
__global__ __launch_bounds__(256) void k_onehot_idx(const int* __restrict__ idxarr,
                                                    float* __restrict__ out) {
    const int g = blockIdx.x * 256 + threadIdx.x;      // float4 index
    const int row = g / (NN/4);
    const int j4  = g % (NN/4);
    const int m = idxarr[row];
    float4 o = {0.f, 0.f, 0.f, 0.f};
    if ((m >> 2) == j4) ((float*)&o)[m & 3] = 1.0f;
    ((float4*)out)[g] = o;
}

// ================= old fp32 fallback path (round-0, known-good) =================
__global__ __launch_bounds__(256) void k_score(const float* __restrict__ patches,
                                               const float* __restrict__ qraw,
                                               const float* __restrict__ pinv,
                                               unsigned long long* __restrict__ keys) {
    __shared__ float Qt[64 * 68];
    __shared__ float Pt[64 * 68];
    __shared__ float redv[64 * 17];
    __shared__ int   redm[64 * 17];
    const int rt  = blockIdx.x;
    const int ms  = blockIdx.y;
    const int b   = blockIdx.z;
    const int r0  = rt * 64;
    const int tid = threadIdx.x;
    const int ty  = tid >> 4;
    const int tx  = tid & 15;

    float bestv[4] = {-INFINITY, -INFINITY, -INFINITY, -INFINITY};
    int   bestm[4] = {0, 0, 0, 0};

    for (int mtv = 0; mtv < 3; mtv++) {
        const int m0 = (ms*3 + mtv) * 64;
        float acc[4][4] = {};
        for (int d0 = 0; d0 < ND; d0 += 64) {
            #pragma unroll
            for (int k = 0; k < 4; k++) {
                int fi = tid + 256*k, row = fi >> 4, c4 = fi & 15;
                *(float4*)&Qt[row*68 + c4*4] =
                    *(const float4*)&qraw[((size_t)b*NN + r0 + row)*ND + d0 + c4*4];
                *(float4*)&Pt[row*68 + c4*4] =
                    *(const float4*)&patches[((size_t)b*NN + m0 + row)*ND + d0 + c4*4];
            }
            __syncthreads();
            #pragma unroll 4
            for (int k4 = 0; k4 < 16; k4++) {
                float4 q[4], p[4];
                #pragma unroll
                for (int i = 0; i < 4; i++) q[i] = *(float4*)&Qt[(ty + 16*i)*68 + k4*4];
                #pragma unroll
                for (int j = 0; j < 4; j++) p[j] = *(float4*)&Pt[(tx + 16*j)*68 + k4*4];
                #pragma unroll
                for (int i = 0; i < 4; i++)
                    #pragma unroll
                    for (int j = 0; j < 4; j++)
                        acc[i][j] += q[i].x*p[j].x + q[i].y*p[j].y
                                   + q[i].z*p[j].z + q[i].w*p[j].w;
            }
            __syncthreads();
        }
        #pragma unroll
        for (int j = 0; j < 4; j++) {
            const int m = m0 + tx + 16*j;
            const float pvv = pinv[(size_t)b*NN + m];
            #pragma unroll
            for (int i = 0; i < 4; i++) {
                const float v = acc[i][j] * pvv;
                if (v > bestv[i] || (v == bestv[i] && m < bestm[i])) {
                    bestv[i] = v; bestm[i] = m;
                }
            }
        }
    }
    #pragma unroll
    for (int i = 0; i < 4; i++) {
        const int lr = ty + 16*i;
        redv[lr*17 + tx] = bestv[i];
        redm[lr*17 + tx] = bestm[i];
    }
    __syncthreads();
    if (tid < 64) {
        float bvv = redv[tid*17];
        int   bmm = redm[tid*17];
        #pragma unroll
        for (int k = 1; k < 16; k++) {
            const float v = redv[tid*17 + k];
            const int   m = redm[tid*17 + k];
            if (v > bvv || (v == bvv && m < bmm)) { bvv = v; bmm = m; }
        }
        unsigned u = __float_as_uint(bvv);
        u = (u & 0x80000000u) ? ~u : (u | 0x80000000u);
        const unsigned long long key =
            ((unsigned long long)u << 32) | (unsigned)(NN - 1 - bmm);
        atomicMax(&keys[(size_t)b*NN + r0 + tid], key);
    }
}

__global__ __launch_bounds__(256) void k_onehot(const unsigned long long* __restrict__ keys,
                                                float* __restrict__ out) {
    const int g = blockIdx.x * 256 + threadIdx.x;
    const int row = g / (NN/4);
    const int j4  = g % (NN/4);
    const unsigned long long key = keys[row];
    const int m = NN - 1 - (int)(key & 0xFFFFFFFFull);
    float4 o = {0.f, 0.f, 0.f, 0.f};
    if ((m >> 2) == j4) ((float*)&o)[m & 3] = 1.0f;
    ((float4*)out)[g] = o;
}

// ---------------- launcher ----------------
extern "C" void kernel_launch(void* const* d_in, const int* in_sizes, int n_in,
                              void* d_out, int out_size, void* d_ws, size_t ws_size,
                              hipStream_t stream) {
    const float* patches = (const float*)d_in[0];
    const float* task    = (const float*)d_in[1];
    const int*   mask    = (const int*)d_in[2];
    float* out = (float*)d_out;

    const size_t SZ_TASKN = (size_t)NB*NT*ND*sizeof(float);
    const size_t SZ_PINV  = (size_t)NB*NN*sizeof(float);
    const size_t SZ_HALF  = (size_t)NB*NN*ND*sizeof(f16);
    const size_t SZ_PART  = (size_t)NB*NN*4*sizeof(float4);
    const size_t SZ_IDX   = (size_t)NB*NN*sizeof(int);
    const size_t need_new = SZ_TASKN + SZ_PINV + 4*SZ_HALF + SZ_PART + 2*SZ_IDX;

    char* w = (char*)d_ws;
    float* task_n = (float*)w;            w += SZ_TASKN;
    float* pinv   = (float*)w;            w += SZ_PINV;

    if (ws_size >= need_new) {
        f16* p_hi = (f16*)w;              w += SZ_HALF;
        f16* p_lo = (f16*)w;              w += SZ_HALF;
        f16* q_hi = (f16*)w;              w += SZ_HALF;
        f16* q_lo = (f16*)w;              w += SZ_HALF;
        float4* part = (float4*)w;        w += SZ_PART;
        int* idxarr = (int*)w;            w += SZ_IDX;
        int* flags  = (int*)w;            w += SZ_IDX;

        k_task_norm<<<NB*NT, 256, 0, stream>>>(task, task_n);
        k_split_patches<<<NB*NN, 256, 0, stream>>>(patches, pinv, p_hi, p_lo);
        k_attn<<<dim3(NN/32, NB), 256, 0, stream>>>(patches, task_n, pinv, mask,
                                                    nullptr, q_hi, q_lo);
        k_score_mfma<<<dim3(4, 8, NB), 256, 0, stream>>>(p_hi, p_lo, q_hi, q_lo,
                                                         pinv, part);
        k_merge<<<(NB*NN)/256, 256, 0, stream>>>(part, idxarr, flags);
        k_rescore<<<NB*NN, 256, 0, stream>>>(patches, q_hi, q_lo, pinv, flags, idxarr);
        k_onehot_idx<<<(NB*NN*NN/4)/256, 256, 0, stream>>>(idxarr, out);
    } else {
        // fallback: round-0 fp32 path
        float* qraw = (float*)w;          w += (size_t)NB*NN*ND*sizeof(float);
        unsigned long long* keys = (unsigned long long*)w;

        hipMemsetAsync(keys, 0, (size_t)NB*NN*sizeof(unsigned long long), stream);
        k_task_norm<<<NB*NT, 256, 0, stream>>>(task, task_n);
        k_pinv<<<NB*NN, 256, 0, stream>>>(patches, pinv);
        k_attn<<<dim3(NN/32, NB), 256, 0, stream>>>(patches, task_n, pinv, mask,
                                                    qraw, nullptr, nullptr);
        k_score<<<dim3(NN/64, 4, NB), 256, 0, stream>>>(patches, qraw, pinv, keys);
        k_onehot<<<(NB*NN*NN/4)/256, 256, 0, stream>>>(keys, out);
    }
}

// Round 3
// 319.572 us; speedup vs baseline: 2.7138x; 1.0952x over previous
//
#include <hip/hip_runtime.h>
#include <math.h>

#define NB 16
#define NN 768
#define NT 48
#define ND 2048
#define SCALE 0.02209708691207961f   // 1/sqrt(2048)
#define NEGBIG (-3.4028234663852886e38f)
#define TAU 1e-3f

typedef _Float16 f16;
typedef f16  f16x8 __attribute__((ext_vector_type(8)));
typedef f16  f16x4 __attribute__((ext_vector_type(4)));
typedef float f32x4 __attribute__((ext_vector_type(4)));

__device__ __forceinline__ void stage16(const void* g, void* l) {
    __builtin_amdgcn_global_load_lds(
        (const __attribute__((address_space(1))) unsigned int*)g,
        (__attribute__((address_space(3))) unsigned int*)l, 16, 0, 0);
}

// ---------------- kernel A: rms-norm task tokens ----------------
__global__ __launch_bounds__(256) void k_task_norm(const float* __restrict__ x,
                                                   float* __restrict__ y) {
    __shared__ float sred[8];
    const int row = blockIdx.x;                 // b*NT + t
    const float4* src = (const float4*)(x + (size_t)row * ND);
    float4* dst = (float4*)(y + (size_t)row * ND);
    const int tid = threadIdx.x;
    float4 v0 = src[tid];
    float4 v1 = src[tid + 256];
    float s = v0.x*v0.x + v0.y*v0.y + v0.z*v0.z + v0.w*v0.w
            + v1.x*v1.x + v1.y*v1.y + v1.z*v1.z + v1.w*v1.w;
    #pragma unroll
    for (int off = 32; off > 0; off >>= 1) s += __shfl_down(s, off, 64);
    if ((tid & 63) == 0) sred[tid >> 6] = s;
    __syncthreads();
    if (tid == 0)
        sred[4] = 1.0f / sqrtf((sred[0]+sred[1]+sred[2]+sred[3]) * (1.0f/ND) + 1e-6f);
    __syncthreads();
    const float inv = sred[4];
    v0.x *= inv; v0.y *= inv; v0.z *= inv; v0.w *= inv;
    v1.x *= inv; v1.y *= inv; v1.z *= inv; v1.w *= inv;
    dst[tid] = v0;
    dst[tid + 256] = v1;
}

// ---------------- kernel C2: fused pinv + split + attention -> q_hi/q_lo ----------------
// block: (row-tile of 32 patch rows, b). 256 threads.
__global__ __launch_bounds__(256) void k_attn2(const float* __restrict__ patches,
                                               const float* __restrict__ task_n,
                                               const int* __restrict__ mask,
                                               float* __restrict__ pinv,
                                               f16* __restrict__ p_hi,
                                               f16* __restrict__ p_lo,
                                               f16* __restrict__ q_hi,
                                               f16* __restrict__ q_lo) {
    __shared__ float smem[12672];   // phase1: Pt[32][68] + Tt[48][68]; phase2: Tt2[48][264]
    __shared__ float lg[32 * 52];   // logits -> attn, stride 52
    const int rt  = blockIdx.x;
    const int b   = blockIdx.y;
    const int r0  = rt * 32;
    const int tid = threadIdx.x;

    float* Pt = smem;               // [32][68]
    float* Tt = smem + 32 * 68;     // [48][68]
    const size_t pbase = ((size_t)b * NN + r0) * ND;
    const size_t tbase = (size_t)b * NT * ND;

    const int rg = tid >> 4;        // row pair {rg, rg+16}
    const int tg = tid & 15;
    float acc0[3] = {0.f, 0.f, 0.f};
    float acc1[3] = {0.f, 0.f, 0.f};
    float ss0 = 0.f, ss1 = 0.f;
    for (int d0 = 0; d0 < ND; d0 += 64) {
        {   // stage Pt + split-write + sumsq (each elem of patches touched once)
            const size_t go0 = pbase + (size_t)rg*ND + d0 + tg*4;
            float4 v0 = *(const float4*)&patches[go0];
            *(float4*)&Pt[rg*68 + tg*4] = v0;
            ss0 += v0.x*v0.x + v0.y*v0.y + v0.z*v0.z + v0.w*v0.w;
            f16x4 h0, l0;
            #pragma unroll
            for (int e = 0; e < 4; e++) {
                float f = (&v0.x)[e];
                f16 a = (f16)f; h0[e] = a; l0[e] = (f16)(f - (float)a);
            }
            *(f16x4*)&p_hi[go0] = h0;
            *(f16x4*)&p_lo[go0] = l0;

            const size_t go1 = pbase + (size_t)(rg+16)*ND + d0 + tg*4;
            float4 v1 = *(const float4*)&patches[go1];
            *(float4*)&Pt[(rg+16)*68 + tg*4] = v1;
            ss1 += v1.x*v1.x + v1.y*v1.y + v1.z*v1.z + v1.w*v1.w;
            f16x4 h1, l1;
            #pragma unroll
            for (int e = 0; e < 4; e++) {
                float f = (&v1.x)[e];
                f16 a = (f16)f; h1[e] = a; l1[e] = (f16)(f - (float)a);
            }
            *(f16x4*)&p_hi[go1] = h1;
            *(f16x4*)&p_lo[go1] = l1;
        }
        #pragma unroll
        for (int k = 0; k < 3; k++) {   // stage Tt (768 float4, 3/thread)
            int fi = tid + 256*k, row = fi >> 4, c4 = fi & 15;
            *(float4*)&Tt[row*68 + c4*4] =
                *(const float4*)&task_n[tbase + (size_t)row*ND + d0 + c4*4];
        }
        __syncthreads();
        #pragma unroll 4
        for (int k4 = 0; k4 < 16; k4++) {
            float4 q0 = *(float4*)&Pt[rg*68 + k4*4];
            float4 q1 = *(float4*)&Pt[(rg+16)*68 + k4*4];
            #pragma unroll
            for (int j = 0; j < 3; j++) {
                float4 t4 = *(float4*)&Tt[(tg + 16*j)*68 + k4*4];
                acc0[j] += q0.x*t4.x + q0.y*t4.y + q0.z*t4.z + q0.w*t4.w;
                acc1[j] += q1.x*t4.x + q1.y*t4.y + q1.z*t4.z + q1.w*t4.w;
            }
        }
        __syncthreads();
    }
    // row sumsq: reduce across the 16 tg lanes (aligned 16-lane groups in wave)
    #pragma unroll
    for (int m = 1; m <= 8; m <<= 1) {
        ss0 += __shfl_xor(ss0, m, 64);
        ss1 += __shfl_xor(ss1, m, 64);
    }
    const float pr0f = 1.0f / sqrtf(ss0 * (1.0f/ND) + 1e-6f);
    const float pr1f = 1.0f / sqrtf(ss1 * (1.0f/ND) + 1e-6f);
    if (tg == 0) {
        pinv[(size_t)b*NN + r0 + rg]      = pr0f;
        pinv[(size_t)b*NN + r0 + rg + 16] = pr1f;
    }
    {   // scaled logits + mask bias
        const float pr0 = pr0f * SCALE;
        const float pr1 = pr1f * SCALE;
        #pragma unroll
        for (int j = 0; j < 3; j++) {
            const int t = tg + 16*j;
            const float bias = mask[b*NT + t] ? 0.0f : NEGBIG;
            lg[rg*52 + t]      = acc0[j] * pr0 + bias;
            lg[(rg+16)*52 + t] = acc1[j] * pr1 + bias;
        }
    }
    __syncthreads();
    // ---- wave-parallel softmax: 8 lanes per row, 6 elems each ----
    {
        const int row = tid >> 3, l = tid & 7;
        float mx = -INFINITY;
        #pragma unroll
        for (int u = 0; u < 6; u++) mx = fmaxf(mx, lg[row*52 + l*6 + u]);
        #pragma unroll
        for (int m = 1; m <= 4; m <<= 1) mx = fmaxf(mx, __shfl_xor(mx, m, 64));
        float sum = 0.f;
        float ev[6];
        #pragma unroll
        for (int u = 0; u < 6; u++) {
            ev[u] = expf(lg[row*52 + l*6 + u] - mx);
            sum += ev[u];
        }
        #pragma unroll
        for (int m = 1; m <= 4; m <<= 1) sum += __shfl_xor(sum, m, 64);
        const float inv = 1.0f / sum;
        #pragma unroll
        for (int u = 0; u < 6; u++) lg[row*52 + l*6 + u] = ev[u] * inv;
    }
    __syncthreads();
    // ---- phase 2: queries = attn @ task_n, write fp16 hi/lo ----
    float* Tt2 = smem;              // [48][264]
    const int rg2 = tid >> 5;
    const int dg  = tid & 31;
    for (int d0 = 0; d0 < ND; d0 += 256) {
        #pragma unroll
        for (int k = 0; k < 12; k++) {
            int fi = tid + 256*k, row = fi >> 6, c4 = fi & 63;
            *(float4*)&Tt2[row*264 + c4*4] =
                *(const float4*)&task_n[tbase + (size_t)row*ND + d0 + c4*4];
        }
        __syncthreads();
        float4 a[4][2] = {};
        for (int t = 0; t < NT; t++) {
            float4 u0 = *(float4*)&Tt2[t*264 + dg*8];
            float4 u1 = *(float4*)&Tt2[t*264 + dg*8 + 4];
            #pragma unroll
            for (int i = 0; i < 4; i++) {
                const float w = lg[(rg2*4 + i)*52 + t];
                a[i][0].x += w*u0.x; a[i][0].y += w*u0.y; a[i][0].z += w*u0.z; a[i][0].w += w*u0.w;
                a[i][1].x += w*u1.x; a[i][1].y += w*u1.y; a[i][1].z += w*u1.z; a[i][1].w += w*u1.w;
            }
        }
        #pragma unroll
        for (int i = 0; i < 4; i++) {
            const size_t o = ((size_t)b*NN + r0 + rg2*4 + i)*ND + d0 + dg*8;
            f16x8 vh, vl;
            #pragma unroll
            for (int e = 0; e < 4; e++) {
                float f0 = (&a[i][0].x)[e], f1 = (&a[i][1].x)[e];
                f16 h0 = (f16)f0, h1 = (f16)f1;
                vh[e]   = h0; vl[e]   = (f16)(f0 - (float)h0);
                vh[4+e] = h1; vl[4+e] = (f16)(f1 - (float)h1);
            }
            *(f16x8*)&q_hi[o] = vh;
            *(f16x8*)&q_lo[o] = vl;
        }
        __syncthreads();
    }
}

// ---------------- kernel D2: pipelined MFMA score (K'=6144 flat 3-pass) ----------------
// tile 192x192, BK=64, 8 waves, 3 LDS buffers, 2-deep prefetch, counted vmcnt.
// grid (4 mt, 4 rt, 16 b) = 256 blocks = exactly 1/CU.
__global__ __launch_bounds__(512, 2) void k_score2(
        const f16* __restrict__ q_hi, const f16* __restrict__ q_lo,
        const f16* __restrict__ p_hi, const f16* __restrict__ p_lo,
        const float* __restrict__ pinv, float4* __restrict__ part) {
    __shared__ __align__(16) char smem[147456];   // 3 bufs x (A 24KB + B 24KB)
    const int tid = threadIdx.x, wid = tid >> 6, lane = tid & 63;
    const int q15 = lane & 15, g4 = lane >> 4;
    const int wr = wid >> 2, wc = wid & 3;        // wave grid 2x4 (96x48 tiles)

    // bijective XCD-chunked remap: co-XCD blocks share a batch's q/p tiles
    const int flat = blockIdx.x + 4*blockIdx.y + 16*blockIdx.z;
    const int logical = (flat & 7) * 32 + (flat >> 3);
    const int mt = logical & 3, rt = (logical >> 2) & 3, b = logical >> 4;

    const size_t arow = (size_t)(b*NN + rt*192) * ND;
    const size_t brow = (size_t)(b*NN + mt*192) * ND;
    const f16* Ahi = q_hi + arow;
    const f16* Alo = q_lo + arow;
    const f16* Bhi = p_hi + brow;
    const f16* Blo = p_lo + brow;

    f32x4 acc[6][3];
    #pragma unroll
    for (int i = 0; i < 6; i++)
        #pragma unroll
        for (int j = 0; j < 3; j++) acc[i][j] = (f32x4){0.f, 0.f, 0.f, 0.f};

    const int lr = lane >> 3, lgch = (lane & 7) ^ lr;
    auto stage_step = [&](int s, int buf) {
        // K'-step s: pass 0 = Ah*Bh, 1 = Al*Bh, 2 = Ah*Bl
        const int pass = s >> 5;
        const f16* gA = (pass == 1) ? Alo : Ahi;
        const f16* gB = (pass == 2) ? Blo : Bhi;
        const int kofs = (s & 31) * 64;
        char* Ab = smem + buf * 49152;
        char* Bb = Ab + 24576;
        #pragma unroll
        for (int ti = 0; ti < 3; ti++) {
            const int u = wid * 3 + ti;             // 0..23 -> rows u*8..u*8+7
            const int row = u * 8 + lr;
            stage16(gA + (size_t)row * ND + kofs + lgch * 8, Ab + u * 1024);
            stage16(gB + (size_t)row * ND + kofs + lgch * 8, Bb + u * 1024);
        }
    };
    const int cxor = q15 & 7;
    auto compute_step = [&](int buf) {
        const char* Ab = smem + buf * 49152;
        const char* Bb = Ab + 24576;
        #pragma unroll
        for (int ksub = 0; ksub < 2; ksub++) {
            f16x8 ah[6], bh[3];
            const int chb = ((ksub*4 + g4) ^ cxor) << 4;
            #pragma unroll
            for (int i = 0; i < 6; i++)
                ah[i] = *(const f16x8*)(Ab + (wr*96 + i*16 + q15)*128 + chb);
            #pragma unroll
            for (int j = 0; j < 3; j++)
                bh[j] = *(const f16x8*)(Bb + (wc*48 + j*16 + q15)*128 + chb);
            __builtin_amdgcn_s_setprio(1);
            #pragma unroll
            for (int i = 0; i < 6; i++)
                #pragma unroll
                for (int j = 0; j < 3; j++)
                    acc[i][j] = __builtin_amdgcn_mfma_f32_16x16x32_f16(ah[i], bh[j], acc[i][j], 0, 0, 0);
            __builtin_amdgcn_s_setprio(0);
        }
    };

    stage_step(0, 0);
    stage_step(1, 1);
    int rb = 0, sb = 2;
    #pragma unroll 1
    for (int t = 0; t < 94; t++) {
        stage_step(t + 2, sb);
        __builtin_amdgcn_sched_barrier(0);
        asm volatile("s_waitcnt vmcnt(12)" ::: "memory");   // tile t landed; t+1,t+2 in flight
        __builtin_amdgcn_s_barrier();
        __builtin_amdgcn_sched_barrier(0);
        compute_step(rb);
        asm volatile("s_waitcnt lgkmcnt(0)" ::: "memory");
        __builtin_amdgcn_s_barrier();
        __builtin_amdgcn_sched_barrier(0);
        rb = (rb == 2) ? 0 : rb + 1;
        sb = (sb == 2) ? 0 : sb + 1;
    }
    // t = 94
    asm volatile("s_waitcnt vmcnt(6)" ::: "memory");
    __builtin_amdgcn_s_barrier();
    __builtin_amdgcn_sched_barrier(0);
    compute_step(rb);
    asm volatile("s_waitcnt lgkmcnt(0)" ::: "memory");
    __builtin_amdgcn_s_barrier();
    __builtin_amdgcn_sched_barrier(0);
    rb = (rb == 2) ? 0 : rb + 1;
    // t = 95
    asm volatile("s_waitcnt vmcnt(0)" ::: "memory");
    __builtin_amdgcn_s_barrier();
    __builtin_amdgcn_sched_barrier(0);
    compute_step(rb);
    __syncthreads();

    // epilogue: scale by pinv[m], per-row top-2, merge via LDS (reuse smem)
    float4* red4 = (float4*)smem;
    const int mbase = mt*192 + wc*48;
    float pv[3];
    #pragma unroll
    for (int j = 0; j < 3; j++) pv[j] = pinv[b*NN + mbase + j*16 + q15];
    #pragma unroll
    for (int i = 0; i < 6; i++) {
        #pragma unroll
        for (int r = 0; r < 4; r++) {
            float v1 = -INFINITY, v2 = -INFINITY; int i1 = 0;
            #pragma unroll
            for (int j = 0; j < 3; j++) {
                float v = acc[i][j][r] * pv[j];
                int m = mbase + j*16 + q15;
                if (v > v1) { v2 = v1; v1 = v; i1 = m; }
                else if (v > v2) v2 = v;
            }
            #pragma unroll
            for (int msk = 1; msk <= 8; msk <<= 1) {
                float ov1 = __shfl_xor(v1, msk, 64);
                int   oi1 = __shfl_xor(i1, msk, 64);
                float ov2 = __shfl_xor(v2, msk, 64);
                if (ov1 > v1 || (ov1 == v1 && oi1 < i1)) { v2 = fmaxf(v1, ov2); v1 = ov1; i1 = oi1; }
                else v2 = fmaxf(v2, ov1);
            }
            if (q15 == 0)
                red4[wc*192 + wr*96 + i*16 + g4*4 + r] = make_float4(v1, __int_as_float(i1), v2, 0.f);
        }
    }
    __syncthreads();
    if (tid < 192) {
        float4 e = red4[tid];
        float v1 = e.x, v2 = e.z; int i1 = __float_as_int(e.y);
        #pragma unroll
        for (int w = 1; w < 4; w++) {
            float4 f = red4[w*192 + tid];
            int fi = __float_as_int(f.y);
            if (f.x > v1 || (f.x == v1 && fi < i1)) { v2 = fmaxf(v1, f.z); v1 = f.x; i1 = fi; }
            else v2 = fmaxf(v2, f.x);
        }
        part[(size_t)(b*NN + rt*192 + tid)*4 + mt] = make_float4(v1, __int_as_float(i1), v2, 0.f);
    }
}

// ---------------- kernel E: merge m-tiles -> idx + rescore flag ----------------
__global__ __launch_bounds__(256) void k_merge(const float4* __restrict__ part,
                                               int* __restrict__ idxarr,
                                               int* __restrict__ flags) {
    const int r = blockIdx.x * 256 + threadIdx.x;
    float4 e = part[(size_t)r*4];
    float v1 = e.x, v2 = e.z; int i1 = __float_as_int(e.y);
    #pragma unroll
    for (int t = 1; t < 4; t++) {
        float4 f = part[(size_t)r*4 + t];
        int fi = __float_as_int(f.y);
        if (f.x > v1 || (f.x == v1 && fi < i1)) { v2 = fmaxf(v1, f.z); v1 = f.x; i1 = fi; }
        else v2 = fmaxf(v2, f.x);
    }
    idxarr[r] = i1;
    flags[r] = (v1 - v2 < TAU) ? 1 : 0;
}

// ---------------- kernel F: exact fp32 rescore of ambiguous rows ----------------
__global__ __launch_bounds__(256) void k_rescore(const float* __restrict__ patches,
                                                 const f16* __restrict__ q_hi,
                                                 const f16* __restrict__ q_lo,
                                                 const float* __restrict__ pinv,
                                                 const int* __restrict__ flags,
                                                 int* __restrict__ idxarr) {
    const int row = blockIdx.x;
    if (!flags[row]) return;
    __shared__ float qrow[ND];
    __shared__ float sv[256];
    __shared__ int   si[256];
    const int b = row / NN;
    const int tid = threadIdx.x;
    const size_t qo = (size_t)row * ND;
    #pragma unroll
    for (int e = 0; e < 8; e++)
        qrow[tid*8 + e] = (float)q_hi[qo + tid*8 + e] + (float)q_lo[qo + tid*8 + e];
    __syncthreads();
    float bv = -INFINITY; int bm = 0;
    for (int mm = tid; mm < NN; mm += 256) {
        const float4* prow = (const float4*)(patches + ((size_t)b*NN + mm)*ND);
        float s = 0.f;
        for (int d4 = 0; d4 < ND/4; d4++) {
            float4 p = prow[d4];
            float4 qv = *(const float4*)&qrow[d4*4];
            s = fmaf(p.x, qv.x, s); s = fmaf(p.y, qv.y, s);
            s = fmaf(p.z, qv.z, s); s = fmaf(p.w, qv.w, s);
        }
        s *= pinv[(size_t)b*NN + mm];
        if (s > bv) { bv = s; bm = mm; }
    }
    sv[tid] = bv; si[tid] = bm;
    __syncthreads();
    for (int st = 128; st > 0; st >>= 1) {
        if (tid < st) {
            float v = sv[tid+st]; int m = si[tid+st];
            if (v > sv[tid] || (v == sv[tid] && m < si[tid])) { sv[tid] = v; si[tid] = m; }
        }
        __syncthreads();
    }
    if (tid == 0) idxarr[row] = si[0];
}

// ---------------- kernel G: one-hot from idx ----------------
__global__ __launch_bounds__(256) void k_onehot_idx(const int* __restrict__ idxarr,
                                                    float* __restrict__ out) {
    const int g = blockIdx.x * 256 + threadIdx.x;      // float4 index
    const int row = g / (NN/4);
    const int j4  = g % (NN/4);
    const int m = idxarr[row];
    float4 o = {0.f, 0.f, 0.f, 0.f};
    if ((m >> 2) == j4) ((float*)&o)[m & 3] = 1.0f;
    ((float4*)out)[g] = o;
}

// ================= fp32 fallback path (round-0, known-good) =================
__global__ __launch_bounds__(256) void k_pinv(const float* __restrict__ x,
                                              float* __restrict__ pinv) {
    __shared__ float sred[8];
    const int row = blockIdx.x;
    const float4* src = (const float4*)(x + (size_t)row * ND);
    const int tid = threadIdx.x;
    float4 v0 = src[tid];
    float4 v1 = src[tid + 256];
    float s = v0.x*v0.x + v0.y*v0.y + v0.z*v0.z + v0.w*v0.w
            + v1.x*v1.x + v1.y*v1.y + v1.z*v1.z + v1.w*v1.w;
    #pragma unroll
    for (int off = 32; off > 0; off >>= 1) s += __shfl_down(s, off, 64);
    if ((tid & 63) == 0) sred[tid >> 6] = s;
    __syncthreads();
    if (tid == 0)
        pinv[row] = 1.0f / sqrtf((sred[0]+sred[1]+sred[2]+sred[3]) * (1.0f/ND) + 1e-6f);
}

__global__ __launch_bounds__(256) void k_attn_f32(const float* __restrict__ patches,
                                                  const float* __restrict__ task_n,
                                                  const float* __restrict__ pinv,
                                                  const int* __restrict__ mask,
                                                  float* __restrict__ qraw) {
    __shared__ float smem[12672];
    __shared__ float lg[32 * 52];
    const int rt  = blockIdx.x;
    const int b   = blockIdx.y;
    const int r0  = rt * 32;
    const int tid = threadIdx.x;
    float* Pt = smem;
    float* Tt = smem + 32 * 68;
    const size_t pbase = ((size_t)b * NN + r0) * ND;
    const size_t tbase = (size_t)b * NT * ND;
    const int rg = tid >> 4;
    const int tg = tid & 15;
    float acc0[3] = {0.f, 0.f, 0.f};
    float acc1[3] = {0.f, 0.f, 0.f};
    for (int d0 = 0; d0 < ND; d0 += 64) {
        {
            int fi = tid, row = fi >> 4, c4 = fi & 15;
            *(float4*)&Pt[row*68 + c4*4] =
                *(const float4*)&patches[pbase + (size_t)row*ND + d0 + c4*4];
            fi = tid + 256; row = fi >> 4; c4 = fi & 15;
            *(float4*)&Pt[row*68 + c4*4] =
                *(const float4*)&patches[pbase + (size_t)row*ND + d0 + c4*4];
        }
        #pragma unroll
        for (int k = 0; k < 3; k++) {
            int fi = tid + 256*k, row = fi >> 4, c4 = fi & 15;
            *(float4*)&Tt[row*68 + c4*4] =
                *(const float4*)&task_n[tbase + (size_t)row*ND + d0 + c4*4];
        }
        __syncthreads();
        #pragma unroll 4
        for (int k4 = 0; k4 < 16; k4++) {
            float4 q0 = *(float4*)&Pt[rg*68 + k4*4];
            float4 q1 = *(float4*)&Pt[(rg+16)*68 + k4*4];
            #pragma unroll
            for (int j = 0; j < 3; j++) {
                float4 t4 = *(float4*)&Tt[(tg + 16*j)*68 + k4*4];
                acc0[j] += q0.x*t4.x + q0.y*t4.y + q0.z*t4.z + q0.w*t4.w;
                acc1[j] += q1.x*t4.x + q1.y*t4.y + q1.z*t4.z + q1.w*t4.w;
            }
        }
        __syncthreads();
    }
    {
        const float pr0 = pinv[(size_t)b*NN + r0 + rg] * SCALE;
        const float pr1 = pinv[(size_t)b*NN + r0 + rg + 16] * SCALE;
        #pragma unroll
        for (int j = 0; j < 3; j++) {
            const int t = tg + 16*j;
            const float bias = mask[b*NT + t] ? 0.0f : NEGBIG;
            lg[rg*52 + t]      = acc0[j] * pr0 + bias;
            lg[(rg+16)*52 + t] = acc1[j] * pr1 + bias;
        }
    }
    __syncthreads();
    if (tid < 32) {
        float mx = -INFINITY;
        for (int t = 0; t < NT; t++) mx = fmaxf(mx, lg[tid*52 + t]);
        float sum = 0.f;
        for (int t = 0; t < NT; t++) {
            float e = expf(lg[tid*52 + t] - mx);
            lg[tid*52 + t] = e;
            sum += e;
        }
        const float inv = 1.0f / sum;
        for (int t = 0; t < NT; t++) lg[tid*52 + t] *= inv;
    }
    __syncthreads();
    float* Tt2 = smem;
    const int rg2 = tid >> 5;
    const int dg  = tid & 31;
    for (int d0 = 0; d0 < ND; d0 += 256) {
        #pragma unroll
        for (int k = 0; k < 12; k++) {
            int fi = tid + 256*k, row = fi >> 6, c4 = fi & 63;
            *(float4*)&Tt2[row*264 + c4*4] =
                *(const float4*)&task_n[tbase + (size_t)row*ND + d0 + c4*4];
        }
        __syncthreads();
        float4 a[4][2] = {};
        for (int t = 0; t < NT; t++) {
            float4 u0 = *(float4*)&Tt2[t*264 + dg*8];
            float4 u1 = *(float4*)&Tt2[t*264 + dg*8 + 4];
            #pragma unroll
            for (int i = 0; i < 4; i++) {
                const float w = lg[(rg2*4 + i)*52 + t];
                a[i][0].x += w*u0.x; a[i][0].y += w*u0.y; a[i][0].z += w*u0.z; a[i][0].w += w*u0.w;
                a[i][1].x += w*u1.x; a[i][1].y += w*u1.y; a[i][1].z += w*u1.z; a[i][1].w += w*u1.w;
            }
        }
        #pragma unroll
        for (int i = 0; i < 4; i++) {
            const size_t o = ((size_t)b*NN + r0 + rg2*4 + i)*ND + d0 + dg*8;
            *(float4*)&qraw[o]     = a[i][0];
            *(float4*)&qraw[o + 4] = a[i][1];
        }
        __syncthreads();
    }
}

__global__ __launch_bounds__(256) void k_score(const float* __restrict__ patches,
                                               const float* __restrict__ qraw,
                                               const float* __restrict__ pinv,
                                               unsigned long long* __restrict__ keys) {
    __shared__ float Qt[64 * 68];
    __shared__ float Pt[64 * 68];
    __shared__ float redv[64 * 17];
    __shared__ int   redm[64 * 17];
    const int rt  = blockIdx.x;
    const int ms  = blockIdx.y;
    const int b   = blockIdx.z;
    const int r0  = rt * 64;
    const int tid = threadIdx.x;
    const int ty  = tid >> 4;
    const int tx  = tid & 15;
    float bestv[4] = {-INFINITY, -INFINITY, -INFINITY, -INFINITY};
    int   bestm[4] = {0, 0, 0, 0};
    for (int mtv = 0; mtv < 3; mtv++) {
        const int m0 = (ms*3 + mtv) * 64;
        float acc[4][4] = {};
        for (int d0 = 0; d0 < ND; d0 += 64) {
            #pragma unroll
            for (int k = 0; k < 4; k++) {
                int fi = tid + 256*k, row = fi >> 4, c4 = fi & 15;
                *(float4*)&Qt[row*68 + c4*4] =
                    *(const float4*)&qraw[((size_t)b*NN + r0 + row)*ND + d0 + c4*4];
                *(float4*)&Pt[row*68 + c4*4] =
                    *(const float4*)&patches[((size_t)b*NN + m0 + row)*ND + d0 + c4*4];
            }
            __syncthreads();
            #pragma unroll 4
            for (int k4 = 0; k4 < 16; k4++) {
                float4 q[4], p[4];
                #pragma unroll
                for (int i = 0; i < 4; i++) q[i] = *(float4*)&Qt[(ty + 16*i)*68 + k4*4];
                #pragma unroll
                for (int j = 0; j < 4; j++) p[j] = *(float4*)&Pt[(tx + 16*j)*68 + k4*4];
                #pragma unroll
                for (int i = 0; i < 4; i++)
                    #pragma unroll
                    for (int j = 0; j < 4; j++)
                        acc[i][j] += q[i].x*p[j].x + q[i].y*p[j].y
                                   + q[i].z*p[j].z + q[i].w*p[j].w;
            }
            __syncthreads();
        }
        #pragma unroll
        for (int j = 0; j < 4; j++) {
            const int m = m0 + tx + 16*j;
            const float pvv = pinv[(size_t)b*NN + m];
            #pragma unroll
            for (int i = 0; i < 4; i++) {
                const float v = acc[i][j] * pvv;
                if (v > bestv[i] || (v == bestv[i] && m < bestm[i])) {
                    bestv[i] = v; bestm[i] = m;
                }
            }
        }
    }
    #pragma unroll
    for (int i = 0; i < 4; i++) {
        const int lr2 = ty + 16*i;
        redv[lr2*17 + tx] = bestv[i];
        redm[lr2*17 + tx] = bestm[i];
    }
    __syncthreads();
    if (tid < 64) {
        float bvv = redv[tid*17];
        int   bmm = redm[tid*17];
        #pragma unroll
        for (int k = 1; k < 16; k++) {
            const float v = redv[tid*17 + k];
            const int   m = redm[tid*17 + k];
            if (v > bvv || (v == bvv && m < bmm)) { bvv = v; bmm = m; }
        }
        unsigned u = __float_as_uint(bvv);
        u = (u & 0x80000000u) ? ~u : (u | 0x80000000u);
        const unsigned long long key =
            ((unsigned long long)u << 32) | (unsigned)(NN - 1 - bmm);
        atomicMax(&keys[(size_t)b*NN + r0 + tid], key);
    }
}

__global__ __launch_bounds__(256) void k_onehot(const unsigned long long* __restrict__ keys,
                                                float* __restrict__ out) {
    const int g = blockIdx.x * 256 + threadIdx.x;
    const int row = g / (NN/4);
    const int j4  = g % (NN/4);
    const unsigned long long key = keys[row];
    const int m = NN - 1 - (int)(key & 0xFFFFFFFFull);
    float4 o = {0.f, 0.f, 0.f, 0.f};
    if ((m >> 2) == j4) ((float*)&o)[m & 3] = 1.0f;
    ((float4*)out)[g] = o;
}

// ---------------- launcher ----------------
extern "C" void kernel_launch(void* const* d_in, const int* in_sizes, int n_in,
                              void* d_out, int out_size, void* d_ws, size_t ws_size,
                              hipStream_t stream) {
    const float* patches = (const float*)d_in[0];
    const float* task    = (const float*)d_in[1];
    const int*   mask    = (const int*)d_in[2];
    float* out = (float*)d_out;

    const size_t SZ_TASKN = (size_t)NB*NT*ND*sizeof(float);
    const size_t SZ_PINV  = (size_t)NB*NN*sizeof(float);
    const size_t SZ_HALF  = (size_t)NB*NN*ND*sizeof(f16);
    const size_t SZ_PART  = (size_t)NB*NN*4*sizeof(float4);
    const size_t SZ_IDX   = (size_t)NB*NN*sizeof(int);
    const size_t need_new = SZ_TASKN + SZ_PINV + 4*SZ_HALF + SZ_PART + 2*SZ_IDX;

    char* w = (char*)d_ws;
    float* task_n = (float*)w;            w += SZ_TASKN;
    float* pinv   = (float*)w;            w += SZ_PINV;

    if (ws_size >= need_new) {
        f16* p_hi = (f16*)w;              w += SZ_HALF;
        f16* p_lo = (f16*)w;              w += SZ_HALF;
        f16* q_hi = (f16*)w;              w += SZ_HALF;
        f16* q_lo = (f16*)w;              w += SZ_HALF;
        float4* part = (float4*)w;        w += SZ_PART;
        int* idxarr = (int*)w;            w += SZ_IDX;
        int* flags  = (int*)w;            w += SZ_IDX;

        k_task_norm<<<NB*NT, 256, 0, stream>>>(task, task_n);
        k_attn2<<<dim3(NN/32, NB), 256, 0, stream>>>(patches, task_n, mask, pinv,
                                                     p_hi, p_lo, q_hi, q_lo);
        k_score2<<<dim3(4, 4, NB), 512, 0, stream>>>(q_hi, q_lo, p_hi, p_lo, pinv, part);
        k_merge<<<(NB*NN)/256, 256, 0, stream>>>(part, idxarr, flags);
        k_rescore<<<NB*NN, 256, 0, stream>>>(patches, q_hi, q_lo, pinv, flags, idxarr);
        k_onehot_idx<<<(NB*NN*NN/4)/256, 256, 0, stream>>>(idxarr, out);
    } else {
        // fallback: round-0 fp32 path
        float* qraw = (float*)w;          w += (size_t)NB*NN*ND*sizeof(float);
        unsigned long long* keys = (unsigned long long*)w;

        hipMemsetAsync(keys, 0, (size_t)NB*NN*sizeof(unsigned long long), stream);
        k_task_norm<<<NB*NT, 256, 0, stream>>>(task, task_n);
        k_pinv<<<NB*NN, 256, 0, stream>>>(patches, pinv);
        k_attn_f32<<<dim3(NN/32, NB), 256, 0, stream>>>(patches, task_n, pinv, mask, qraw);
        k_score<<<dim3(NN/64, 4, NB), 256, 0, stream>>>(patches, qraw, pinv, keys);
        k_onehot<<<(NB*NN*NN/4)/256, 256, 0, stream>>>(keys, out);
    }
}